// Round 4
// baseline (5185.558 us; speedup 1.0000x reference)
//
#include <hip/hip_runtime.h>

#define NB 131072
#define HD 100

typedef float f2 __attribute__((ext_vector_type(2)));

// ---------------------------------------------------------------------------
// Kernel 1a (NEW, A/B candidate): 4 GCN layers, DS-traffic-reduced.
// Block = 128 threads = 2 waves over the SAME 8 batches.
// lane = b*8 + i (b = batch 0..7, i = node 0..7). Wave wv owns output column
// pairs p=0..24 at float offset j0 = 50*wv (exact 50/50 split, no overlap).
// Key idea: the t = (h@W) intermediate is staged INTO hsh at the slots where
// h-new will go, with a per-octet rotation swizzle phys(p) = (p + b) % 25.
// The adj-mix then reads t via broadcast ds_read_b64 (all 8 lanes of an octet
// read the same address -> LDS broadcast; octet swizzle makes the 8 octet
// addresses bank-disjoint). This replaces 16 ds_bpermute per pair with
// 8 b64 reads -> ~1.9x less DS-pipe demand.
// Swizzle invariant: canonical pair p of slice s lives at float column
// 50*s + 2*((p + b) % 25) (+0/+1) of row 8*b+i. The next layer's K-loop
// un-rotates per-lane (o = (b+p) % 25) so the weight index stays uniform.
// ---------------------------------------------------------------------------
__global__ void __launch_bounds__(128, 3)
k_gcn2(const float* feat, const float* adj,
       const float* gc1w, const float* gc1b,
       const float* gc2w, const float* gc2b,
       const float* gc3w, const float* gc3b,
       const float* gc4w, const float* gc4b,
       float* gA, float* gB)
{
    __shared__ float hsh[64][102];   // 26112 B -> 6 blocks/CU (12 waves)
    const int tid  = threadIdx.x;
    const int wv   = tid >> 6;
    const int lane = tid & 63;
    const int j0   = __builtin_amdgcn_readfirstlane(wv * 50);
    const int b    = lane >> 3;
    const int i    = lane & 7;
    const int batch = blockIdx.x * 8 + b;
    const int r    = lane;

    // adj row of this (batch, node) -> registers
    float adjr[8];
    {
        const float4 a0 = *(const float4*)(adj + (size_t)batch * 64 + i * 8);
        const float4 a1 = *(const float4*)(adj + (size_t)batch * 64 + i * 8 + 4);
        adjr[0] = a0.x; adjr[1] = a0.y; adjr[2] = a0.z; adjr[3] = a0.w;
        adjr[4] = a1.x; adjr[5] = a1.y; adjr[6] = a1.z; adjr[7] = a1.w;
    }

    f2 t[25];

    // ---- gc1: K = FIN = 8 from registers ----
    {
        float f8[8];
        const float4 f0v = *(const float4*)(feat + (size_t)batch * 64 + i * 8);
        const float4 f1v = *(const float4*)(feat + (size_t)batch * 64 + i * 8 + 4);
        f8[0] = f0v.x; f8[1] = f0v.y; f8[2] = f0v.z; f8[3] = f0v.w;
        f8[4] = f1v.x; f8[5] = f1v.y; f8[6] = f1v.z; f8[7] = f1v.w;
#pragma unroll
        for (int p = 0; p < 25; p++) t[p] = (f2){0.f, 0.f};
#pragma unroll
        for (int k = 0; k < 8; k++) {
            const float* wr = gc1w + k * HD + j0;   // uniform -> s_load
            const f2 hk = {f8[k], f8[k]};
#pragma unroll
            for (int p = 0; p < 25; p++)
                t[p] = __builtin_elementwise_fma(hk, *(const f2*)(wr + 2 * p), t[p]);
        }
    }

    // ---- layers: stage t (swizzled) -> mix via broadcast reads -> writeback,
    //      then K-loop of the next layer reads the swizzled h. ----
    const float* Ws[3] = {gc2w, gc3w, gc4w};
    const float* Bs[4] = {gc1b, gc2b, gc3b, gc4b};

    for (int l = 0; l < 4; l++) {
        // stage: write canonical t[p] at swizzled column
        {
            int po = b;
#pragma unroll
            for (int p = 0; p < 25; p++) {
                *(f2*)&hsh[r][j0 + 2 * po] = t[p];
                po = (po == 24) ? 0 : po + 1;
            }
        }
        __syncthreads();   // t visible (and, for l>0, h_old reads all done before)
        // mix: h_new[p] = relu(bias + sum_m adj[i][m] * t[m][p]); keep in regs
        {
            const float* Bb = Bs[l];
            int po = b;
#pragma unroll
            for (int p = 0; p < 25; p++) {
                const int phys = j0 + 2 * po;
                f2 acc = *(const f2*)(Bb + j0 + 2 * p);
#pragma unroll
                for (int m = 0; m < 8; m++) {
                    const f2 tm = *(const f2*)&hsh[(b << 3) + m][phys];  // broadcast
                    const f2 am = {adjr[m], adjr[m]};
                    acc = __builtin_elementwise_fma(am, tm, acc);
                }
                f2 hv; hv.x = fmaxf(acc.x, 0.f); hv.y = fmaxf(acc.y, 0.f);
                t[p] = hv;
                po = (po == 24) ? 0 : po + 1;
            }
        }
        // writeback h_new over the (fully consumed) t slots
        {
            int po = b;
#pragma unroll
            for (int p = 0; p < 25; p++) {
                *(f2*)&hsh[r][j0 + 2 * po] = t[p];
                po = (po == 24) ? 0 : po + 1;
            }
        }
        __syncthreads();   // h_new visible to all waves

        if (l == 3) break;

        // K-loop of next layer: t[q] = sum_k h[k] * W[k][j-slice]
        const float* W = Ws[l];
#pragma unroll
        for (int p = 0; p < 25; p++) t[p] = (f2){0.f, 0.f};
        {
            int o = b;
            for (int p = 0; p < 25; p++) {
                const f2 ha = *(const f2*)&hsh[r][2 * o];        // slice 0, canonical k=2p,2p+1
                const f2 hb = *(const f2*)&hsh[r][50 + 2 * o];   // slice 1, canonical k=50+2p,51+2p
                const float* w0 = W + (2 * p) * HD + j0;         // uniform -> s_load
                const float* w1 = W + (2 * p + 1) * HD + j0;
                const float* w2 = W + (50 + 2 * p) * HD + j0;
                const float* w3 = W + (51 + 2 * p) * HD + j0;
                const f2 hax = {ha.x, ha.x};
                const f2 hay = {ha.y, ha.y};
                const f2 hbx = {hb.x, hb.x};
                const f2 hby = {hb.y, hb.y};
#pragma unroll
                for (int q = 0; q < 25; q++) {
                    t[q] = __builtin_elementwise_fma(hax, *(const f2*)(w0 + 2 * q), t[q]);
                    t[q] = __builtin_elementwise_fma(hay, *(const f2*)(w1 + 2 * q), t[q]);
                    t[q] = __builtin_elementwise_fma(hbx, *(const f2*)(w2 + 2 * q), t[q]);
                    t[q] = __builtin_elementwise_fma(hby, *(const f2*)(w3 + 2 * q), t[q]);
                }
                o = (o == 24) ? 0 : o + 1;
            }
        }
        __syncthreads();   // all waves done reading h_old before staging t
    }

    // ---- epilogue: g = h[:, node 7, :], un-swizzling ----
    for (int idx = tid; idx < 8 * HD; idx += 128) {
        const int bl = idx / HD;
        const int j  = idx - bl * HD;
        const int s  = (j >= 50) ? 1 : 0;
        const int jj = j - 50 * s;
        const int p  = jj >> 1;
        const int lo = jj & 1;
        int po = p + bl; po = (po >= 25) ? po - 25 : po;
        const float v = hsh[bl * 8 + 7][50 * s + 2 * po + lo];
        const int gb = blockIdx.x * 8 + bl;
        if (j < 64) gA[(size_t)gb * 64 + j] = v;
        else        gB[(size_t)gb * 64 + (j - 64)] = v;
    }
}

// ---------------------------------------------------------------------------
// Kernel 1b (OLD, audited reference path): identical to the round-1 kernel.
// Launched AFTER k_gcn2 so it overwrites gA/gB -> output correctness never
// depends on the new variant. Gives the A/B baseline in the same profile.
// ---------------------------------------------------------------------------
__global__ void __launch_bounds__(256, 4)
k_gcn(const float* feat, const float* adj,
      const float* gc1w, const float* gc1b,
      const float* gc2w, const float* gc2b,
      const float* gc3w, const float* gc3b,
      const float* gc4w, const float* gc4b,
      float* gA, float* gB)
{
    __shared__ float hsh[64][102];   // 26112 B
    const int tid  = threadIdx.x;
    const int wv   = tid >> 6;
    const int lane = tid & 63;
    const int j0   = __builtin_amdgcn_readfirstlane(wv * 26 > 74 ? 74 : wv * 26);
    const int b    = lane >> 3;
    const int i    = lane & 7;
    const int batch = blockIdx.x * 8 + b;
    const int r    = lane;

    float adjr[8];
    {
        const float4 a0 = *(const float4*)(adj + (size_t)batch * 64 + i * 8);
        const float4 a1 = *(const float4*)(adj + (size_t)batch * 64 + i * 8 + 4);
        adjr[0] = a0.x; adjr[1] = a0.y; adjr[2] = a0.z; adjr[3] = a0.w;
        adjr[4] = a1.x; adjr[5] = a1.y; adjr[6] = a1.z; adjr[7] = a1.w;
    }
    int pidx[8];
#pragma unroll
    for (int m = 0; m < 8; m++) pidx[m] = ((lane & 0x38) | m) << 2;

    f2 t[13];

    {
        float f8[8];
        const float4 f0v = *(const float4*)(feat + (size_t)batch * 64 + i * 8);
        const float4 f1v = *(const float4*)(feat + (size_t)batch * 64 + i * 8 + 4);
        f8[0] = f0v.x; f8[1] = f0v.y; f8[2] = f0v.z; f8[3] = f0v.w;
        f8[4] = f1v.x; f8[5] = f1v.y; f8[6] = f1v.z; f8[7] = f1v.w;
#pragma unroll
        for (int jj = 0; jj < 13; jj++) t[jj] = (f2){0.f, 0.f};
#pragma unroll
        for (int k = 0; k < 8; k++) {
            const float* wr = gc1w + k * HD + j0;
            const f2 hk = {f8[k], f8[k]};
#pragma unroll
            for (int jj = 0; jj < 13; jj++)
                t[jj] = __builtin_elementwise_fma(hk, *(const f2*)(wr + 2 * jj), t[jj]);
        }
#pragma unroll
        for (int jj = 0; jj < 13; jj++) {
            f2 acc = *(const f2*)(gc1b + j0 + 2 * jj);
#pragma unroll
            for (int m = 0; m < 8; m++) {
                f2 tm;
                tm.x = __int_as_float(
                    __builtin_amdgcn_ds_bpermute(pidx[m], __float_as_int(t[jj].x)));
                tm.y = __int_as_float(
                    __builtin_amdgcn_ds_bpermute(pidx[m], __float_as_int(t[jj].y)));
                const f2 am = {adjr[m], adjr[m]};
                acc = __builtin_elementwise_fma(am, tm, acc);
            }
            f2 hv; hv.x = fmaxf(acc.x, 0.f); hv.y = fmaxf(acc.y, 0.f);
            *(f2*)&hsh[r][j0 + 2 * jj] = hv;
        }
    }
    __syncthreads();

    for (int l = 0; l < 3; l++) {
        const float* W  = (l == 0) ? gc2w : (l == 1) ? gc3w : gc4w;
        const float* Bb = (l == 0) ? gc2b : (l == 1) ? gc3b : gc4b;
#pragma unroll
        for (int jj = 0; jj < 13; jj++) t[jj] = (f2){0.f, 0.f};
#pragma unroll 2
        for (int k = 0; k < HD; k += 2) {
            const f2 h2 = *(const f2*)&hsh[r][k];
            const float* w0 = W + k * HD + j0;
            const float* w1 = w0 + HD;
            const f2 hx = {h2.x, h2.x};
            const f2 hy = {h2.y, h2.y};
#pragma unroll
            for (int jj = 0; jj < 13; jj++)
                t[jj] = __builtin_elementwise_fma(hx, *(const f2*)(w0 + 2 * jj), t[jj]);
#pragma unroll
            for (int jj = 0; jj < 13; jj++)
                t[jj] = __builtin_elementwise_fma(hy, *(const f2*)(w1 + 2 * jj), t[jj]);
        }
        __syncthreads();
#pragma unroll
        for (int jj = 0; jj < 13; jj++) {
            f2 acc = *(const f2*)(Bb + j0 + 2 * jj);
#pragma unroll
            for (int m = 0; m < 8; m++) {
                f2 tm;
                tm.x = __int_as_float(
                    __builtin_amdgcn_ds_bpermute(pidx[m], __float_as_int(t[jj].x)));
                tm.y = __int_as_float(
                    __builtin_amdgcn_ds_bpermute(pidx[m], __float_as_int(t[jj].y)));
                const f2 am = {adjr[m], adjr[m]};
                acc = __builtin_elementwise_fma(am, tm, acc);
            }
            f2 hv; hv.x = fmaxf(acc.x, 0.f); hv.y = fmaxf(acc.y, 0.f);
            *(f2*)&hsh[r][j0 + 2 * jj] = hv;
        }
        __syncthreads();
    }

    for (int idx = tid; idx < 8 * HD; idx += 256) {
        const int bl = idx / HD;
        const int j  = idx - bl * HD;
        const float v = hsh[bl * 8 + 7][j];
        const int gb = blockIdx.x * 8 + bl;
        if (j < 64) gA[(size_t)gb * 64 + j] = v;
        else        gB[(size_t)gb * 64 + (j - 64)] = v;
    }
}

// ---------------------------------------------------------------------------
// Kernel 2: hw-embedding MLP + graph head + final MLP + sigmoid. (unchanged)
// ---------------------------------------------------------------------------
template<int NPK, bool RELU>
__device__ __forceinline__ void dense_slice(const float* inRow, int K,
    const float* W, int ldw, const float* Bias,
    float* outPtr, int outStride, int bIdx, int j0)
{
    f2 acc[NPK];
#pragma unroll
    for (int jj = 0; jj < NPK; jj++) acc[jj] = (f2){0.f, 0.f};
#pragma unroll 2
    for (int k = 0; k < K; k += 2) {
        const f2 v = *(const f2*)(inRow + k);
        const float* w0 = W + k * ldw + j0;         // uniform -> s_load
        const float* w1 = w0 + ldw;
        const f2 vx = {v.x, v.x};
        const f2 vy = {v.y, v.y};
#pragma unroll
        for (int jj = 0; jj < NPK; jj++)
            acc[jj] = __builtin_elementwise_fma(vx, *(const f2*)(w0 + 2 * jj), acc[jj]);
#pragma unroll
        for (int jj = 0; jj < NPK; jj++)
            acc[jj] = __builtin_elementwise_fma(vy, *(const f2*)(w1 + 2 * jj), acc[jj]);
    }
#pragma unroll
    for (int jj = 0; jj < NPK; jj++) {
        const f2 bz = *(const f2*)(Bias + j0 + 2 * jj);
        f2 z; z.x = acc[jj].x + bz.x; z.y = acc[jj].y + bz.y;
        if (RELU) { z.x = fmaxf(z.x, 0.f); z.y = fmaxf(z.y, 0.f); }
        *(f2*)(outPtr + bIdx * outStride + j0 + 2 * jj) = z;
    }
}

__global__ void __launch_bounds__(512, 4)
k_head(const float* hw_emb, const float* gA, const float* gB,
       const float* fc3w, const float* fc3b, const float* fc4w, const float* fc4b,
       const float* fc5w, const float* fc5b,
       const float* f0w, const float* f0b, const float* f1w, const float* f1b,
       const float* f2w, const float* f2b, const float* f3w, const float* f3b,
       const float* f4w, const float* f4b,
       const float* e0w, const float* e0b, const float* e1w, const float* e1b,
       float* out)
{
    __shared__ float bufA[64][102];
    __shared__ float bufB[64][102];
    __shared__ float xcat[64][44];
    __shared__ float hwe[64][20];
    const int tid  = threadIdx.x;
    const int wv   = tid >> 6;
    const int b    = tid & 63;
    const int base = blockIdx.x * 64;
    const int j14 = __builtin_amdgcn_readfirstlane(wv * 14 > 86 ? 86 : wv * 14);
    const int j4  = __builtin_amdgcn_readfirstlane(wv * 4 > 16 ? 16 : wv * 4);

    if (tid < 320) {
        const float4 v = *(const float4*)(hw_emb + (size_t)base * 20 + tid * 4);
        const int bb = (tid * 4) / 20, kk = (tid * 4) % 20;
        *(float4*)&hwe[bb][kk] = v;
    }
    for (int q = tid; q < 64 * 32; q += 512) {
        const int bb = q >> 5, k2 = (q & 31) * 2;
        const float2 v = *(const float2*)(gA + (size_t)(base + bb) * 64 + k2);
        *(float2*)&bufA[bb][k2] = v;
    }
    for (int q = tid; q < 64 * 18; q += 512) {
        const int bb = q / 18, k2 = (q - bb * 18) * 2;
        const float2 v = *(const float2*)(gB + (size_t)(base + bb) * 64 + k2);
        *(float2*)&bufA[bb][64 + k2] = v;
    }
    __syncthreads();

    dense_slice<7, true >(&hwe[b][0], 20, e0w, HD, e0b, &bufB[0][0], 102, b, j14);
    __syncthreads();
    dense_slice<2, true >(&bufB[b][0], HD, e1w, 20, e1b, &xcat[0][20], 44, b, j4);
    __syncthreads();
    dense_slice<7, true >(&bufA[b][0], HD, fc3w, HD, fc3b, &bufB[0][0], 102, b, j14);
    __syncthreads();
    dense_slice<7, true >(&bufB[b][0], HD, fc4w, HD, fc4b, &bufA[0][0], 102, b, j14);
    __syncthreads();
    dense_slice<2, false>(&bufA[b][0], HD, fc5w, 20, fc5b, &xcat[0][0], 44, b, j4);
    __syncthreads();
    dense_slice<7, true >(&xcat[b][0], 40, f0w, HD, f0b, &bufA[0][0], 102, b, j14);
    __syncthreads();
    dense_slice<7, true >(&bufA[b][0], HD, f1w, HD, f1b, &bufB[0][0], 102, b, j14);
    __syncthreads();
    dense_slice<7, true >(&bufB[b][0], HD, f2w, HD, f2b, &bufA[0][0], 102, b, j14);
    __syncthreads();
    dense_slice<7, true >(&bufA[b][0], HD, f3w, HD, f3b, &bufB[0][0], 102, b, j14);
    __syncthreads();
    if (wv == 0) {
        float z = f4b[0];
        const float* row = &bufB[b][0];
#pragma unroll 2
        for (int k = 0; k < HD; k += 2) {
            const float2 v = *(const float2*)(row + k);
            z = fmaf(v.x, f4w[k], z);
            z = fmaf(v.y, f4w[k + 1], z);
        }
        out[base + b] = 1.f / (1.f + __expf(-z));
    }
}

// ---------------------------------------------------------------------------
extern "C" void kernel_launch(void* const* d_in, const int* in_sizes, int n_in,
                              void* d_out, int out_size, void* d_ws, size_t ws_size,
                              hipStream_t stream)
{
    const float* feat = (const float*)d_in[0];
    const float* adj  = (const float*)d_in[1];
    const float* hw   = (const float*)d_in[2];
    const float* gc1w = (const float*)d_in[3];
    const float* gc1b = (const float*)d_in[4];
    const float* gc2w = (const float*)d_in[5];
    const float* gc2b = (const float*)d_in[6];
    const float* gc3w = (const float*)d_in[7];
    const float* gc3b = (const float*)d_in[8];
    const float* gc4w = (const float*)d_in[9];
    const float* gc4b = (const float*)d_in[10];
    const float* fc3w = (const float*)d_in[11];
    const float* fc3b = (const float*)d_in[12];
    const float* fc4w = (const float*)d_in[13];
    const float* fc4b = (const float*)d_in[14];
    const float* fc5w = (const float*)d_in[15];
    const float* fc5b = (const float*)d_in[16];
    const float* f0w  = (const float*)d_in[17];
    const float* f0b  = (const float*)d_in[18];
    const float* f1w  = (const float*)d_in[19];
    const float* f1b  = (const float*)d_in[20];
    const float* f2w  = (const float*)d_in[21];
    const float* f2b  = (const float*)d_in[22];
    const float* f3w  = (const float*)d_in[23];
    const float* f3b  = (const float*)d_in[24];
    const float* f4w  = (const float*)d_in[25];
    const float* f4b  = (const float*)d_in[26];
    const float* e0w  = (const float*)d_in[27];
    const float* e0b  = (const float*)d_in[28];
    const float* e1w  = (const float*)d_in[29];
    const float* e1b  = (const float*)d_in[30];

    const size_t need = (size_t)NB * 128 * sizeof(float);
    if (ws_size >= need) {
        // A/B mode: run the NEW gcn first (results then fully overwritten by
        // the audited OLD gcn, so correctness never depends on k_gcn2), and
        // read both variants' dur_us/counters from the per-dispatch profile.
        float* gAp = (float*)d_ws;
        float* gBp = (float*)d_ws + (size_t)NB * 64;
        hipLaunchKernelGGL(k_gcn2, dim3(NB / 8), dim3(128), 0, stream,
                           feat, adj, gc1w, gc1b, gc2w, gc2b, gc3w, gc3b, gc4w, gc4b,
                           gAp, gBp);
        hipLaunchKernelGGL(k_gcn, dim3(NB / 8), dim3(256), 0, stream,
                           feat, adj, gc1w, gc1b, gc2w, gc2b, gc3w, gc3b, gc4w, gc4b,
                           gAp, gBp);
        hipLaunchKernelGGL(k_head, dim3(NB / 64), dim3(512), 0, stream,
                           hw, gAp, gBp, fc3w, fc3b, fc4w, fc4b, fc5w, fc5b,
                           f0w, f0b, f1w, f1b, f2w, f2b, f3w, f3b, f4w, f4b,
                           e0w, e0b, e1w, e1b, (float*)d_out);
    } else {
        // Overlay fallback: old path only (k_gcn2 would corrupt feat/adj
        // before k_gcn re-reads them).
        float* gAp = (float*)d_in[0];
        float* gBp = (float*)d_in[1];
        hipLaunchKernelGGL(k_gcn, dim3(NB / 8), dim3(256), 0, stream,
                           feat, adj, gc1w, gc1b, gc2w, gc2b, gc3w, gc3b, gc4w, gc4b,
                           gAp, gBp);
        hipLaunchKernelGGL(k_head, dim3(NB / 64), dim3(512), 0, stream,
                           hw, gAp, gBp, fc3w, fc3b, fc4w, fc4b, fc5w, fc5b,
                           f0w, f0b, f1w, f1b, f2w, f2b, f3w, f3b, f4w, f4b,
                           e0w, e0b, e1w, e1b, (float*)d_out);
    }
}

// Round 5
// 2536.888 us; speedup vs baseline: 2.0441x; 2.0441x over previous
//
#include <hip/hip_runtime.h>

#define NB 131072
#define HD 100

typedef float f2 __attribute__((ext_vector_type(2)));

// ---------------------------------------------------------------------------
// Kernel 1a (NEW A/B candidate): old structure, occupancy-maximized.
// Block = 512 threads = 8 waves over the SAME 8 batches; wave wv owns 14
// output cols at j0 = min(wv*14, 86) (even -> 8B-aligned f2; tail overlap
// writes bitwise-identical values). 7 f2 accumulators -> ~42 VGPRs; with
// __launch_bounds__(512,8) the VGPR cap is 64 -> 4 blocks/CU = 32 waves/CU
// (100% occupancy) to hide s_load/DS latency. Weight chunk per k-step =
// 2 rows x 7 f2 = 28 SGPRs -> deep s_load pipelining within budget.
// ---------------------------------------------------------------------------
__global__ void __launch_bounds__(512, 8)
k_gcn3(const float* feat, const float* adj,
       const float* gc1w, const float* gc1b,
       const float* gc2w, const float* gc2b,
       const float* gc3w, const float* gc3b,
       const float* gc4w, const float* gc4b,
       float* gA, float* gB)
{
    __shared__ float hsh[64][102];   // 26112 B; 4 blocks/CU (thread-capped)
    const int tid  = threadIdx.x;
    const int wv   = tid >> 6;
    const int lane = tid & 63;
    const int j0   = __builtin_amdgcn_readfirstlane(wv * 14 > 86 ? 86 : wv * 14);
    const int b    = lane >> 3;
    const int i    = lane & 7;
    const int batch = blockIdx.x * 8 + b;
    const int r    = lane;

    float adjr[8];
    {
        const float4 a0 = *(const float4*)(adj + (size_t)batch * 64 + i * 8);
        const float4 a1 = *(const float4*)(adj + (size_t)batch * 64 + i * 8 + 4);
        adjr[0] = a0.x; adjr[1] = a0.y; adjr[2] = a0.z; adjr[3] = a0.w;
        adjr[4] = a1.x; adjr[5] = a1.y; adjr[6] = a1.z; adjr[7] = a1.w;
    }
    int pidx[8];
#pragma unroll
    for (int m = 0; m < 8; m++) pidx[m] = ((lane & 0x38) | m) << 2;

    f2 t[7];

    // ---- gc1: K = FIN = 8 from registers ----
    {
        float f8[8];
        const float4 f0v = *(const float4*)(feat + (size_t)batch * 64 + i * 8);
        const float4 f1v = *(const float4*)(feat + (size_t)batch * 64 + i * 8 + 4);
        f8[0] = f0v.x; f8[1] = f0v.y; f8[2] = f0v.z; f8[3] = f0v.w;
        f8[4] = f1v.x; f8[5] = f1v.y; f8[6] = f1v.z; f8[7] = f1v.w;
#pragma unroll
        for (int jj = 0; jj < 7; jj++) t[jj] = (f2){0.f, 0.f};
#pragma unroll
        for (int k = 0; k < 8; k++) {
            const float* wr = gc1w + k * HD + j0;   // uniform -> s_load
            const f2 hk = {f8[k], f8[k]};
#pragma unroll
            for (int jj = 0; jj < 7; jj++)
                t[jj] = __builtin_elementwise_fma(hk, *(const f2*)(wr + 2 * jj), t[jj]);
        }
#pragma unroll
        for (int jj = 0; jj < 7; jj++) {
            f2 acc = *(const f2*)(gc1b + j0 + 2 * jj);
#pragma unroll
            for (int m = 0; m < 8; m++) {
                f2 tm;
                tm.x = __int_as_float(
                    __builtin_amdgcn_ds_bpermute(pidx[m], __float_as_int(t[jj].x)));
                tm.y = __int_as_float(
                    __builtin_amdgcn_ds_bpermute(pidx[m], __float_as_int(t[jj].y)));
                const f2 am = {adjr[m], adjr[m]};
                acc = __builtin_elementwise_fma(am, tm, acc);
            }
            f2 hv; hv.x = fmaxf(acc.x, 0.f); hv.y = fmaxf(acc.y, 0.f);
            *(f2*)&hsh[r][j0 + 2 * jj] = hv;
        }
    }
    __syncthreads();

    // ---- gc2..gc4: K = 100, h read from LDS ----
    for (int l = 0; l < 3; l++) {
        const float* W  = (l == 0) ? gc2w : (l == 1) ? gc3w : gc4w;
        const float* Bb = (l == 0) ? gc2b : (l == 1) ? gc3b : gc4b;
#pragma unroll
        for (int jj = 0; jj < 7; jj++) t[jj] = (f2){0.f, 0.f};
#pragma unroll 2
        for (int k = 0; k < HD; k += 2) {
            const f2 h2 = *(const f2*)&hsh[r][k];
            const float* w0 = W + k * HD + j0;      // uniform -> s_load
            const float* w1 = w0 + HD;
            const f2 hx = {h2.x, h2.x};
            const f2 hy = {h2.y, h2.y};
#pragma unroll
            for (int jj = 0; jj < 7; jj++)
                t[jj] = __builtin_elementwise_fma(hx, *(const f2*)(w0 + 2 * jj), t[jj]);
#pragma unroll
            for (int jj = 0; jj < 7; jj++)
                t[jj] = __builtin_elementwise_fma(hy, *(const f2*)(w1 + 2 * jj), t[jj]);
        }
        __syncthreads();
#pragma unroll
        for (int jj = 0; jj < 7; jj++) {
            f2 acc = *(const f2*)(Bb + j0 + 2 * jj);
#pragma unroll
            for (int m = 0; m < 8; m++) {
                f2 tm;
                tm.x = __int_as_float(
                    __builtin_amdgcn_ds_bpermute(pidx[m], __float_as_int(t[jj].x)));
                tm.y = __int_as_float(
                    __builtin_amdgcn_ds_bpermute(pidx[m], __float_as_int(t[jj].y)));
                const f2 am = {adjr[m], adjr[m]};
                acc = __builtin_elementwise_fma(am, tm, acc);
            }
            f2 hv; hv.x = fmaxf(acc.x, 0.f); hv.y = fmaxf(acc.y, 0.f);
            *(f2*)&hsh[r][j0 + 2 * jj] = hv;
        }
        __syncthreads();
    }

    // ---- write g = h[:, node 7, :] ----
    for (int idx = tid; idx < 8 * HD; idx += 512) {
        const int bl = idx / HD;
        const int j  = idx - bl * HD;
        const float v = hsh[bl * 8 + 7][j];
        const int gb = blockIdx.x * 8 + bl;
        if (j < 64) gA[(size_t)gb * 64 + j] = v;
        else        gB[(size_t)gb * 64 + (j - 64)] = v;
    }
}

// ---------------------------------------------------------------------------
// Kernel 1b (OLD, audited): byte-identical to the PASSING round-4 path.
// Launched AFTER k_gcn3 so it overwrites all of gA/gB -> correctness never
// depends on the A/B candidate.
// ---------------------------------------------------------------------------
__global__ void __launch_bounds__(256, 4)
k_gcn(const float* feat, const float* adj,
      const float* gc1w, const float* gc1b,
      const float* gc2w, const float* gc2b,
      const float* gc3w, const float* gc3b,
      const float* gc4w, const float* gc4b,
      float* gA, float* gB)
{
    __shared__ float hsh[64][102];   // 26112 B
    const int tid  = threadIdx.x;
    const int wv   = tid >> 6;
    const int lane = tid & 63;
    const int j0   = __builtin_amdgcn_readfirstlane(wv * 26 > 74 ? 74 : wv * 26);
    const int b    = lane >> 3;
    const int i    = lane & 7;
    const int batch = blockIdx.x * 8 + b;
    const int r    = lane;

    float adjr[8];
    {
        const float4 a0 = *(const float4*)(adj + (size_t)batch * 64 + i * 8);
        const float4 a1 = *(const float4*)(adj + (size_t)batch * 64 + i * 8 + 4);
        adjr[0] = a0.x; adjr[1] = a0.y; adjr[2] = a0.z; adjr[3] = a0.w;
        adjr[4] = a1.x; adjr[5] = a1.y; adjr[6] = a1.z; adjr[7] = a1.w;
    }
    int pidx[8];
#pragma unroll
    for (int m = 0; m < 8; m++) pidx[m] = ((lane & 0x38) | m) << 2;

    f2 t[13];

    {
        float f8[8];
        const float4 f0v = *(const float4*)(feat + (size_t)batch * 64 + i * 8);
        const float4 f1v = *(const float4*)(feat + (size_t)batch * 64 + i * 8 + 4);
        f8[0] = f0v.x; f8[1] = f0v.y; f8[2] = f0v.z; f8[3] = f0v.w;
        f8[4] = f1v.x; f8[5] = f1v.y; f8[6] = f1v.z; f8[7] = f1v.w;
#pragma unroll
        for (int jj = 0; jj < 13; jj++) t[jj] = (f2){0.f, 0.f};
#pragma unroll
        for (int k = 0; k < 8; k++) {
            const float* wr = gc1w + k * HD + j0;
            const f2 hk = {f8[k], f8[k]};
#pragma unroll
            for (int jj = 0; jj < 13; jj++)
                t[jj] = __builtin_elementwise_fma(hk, *(const f2*)(wr + 2 * jj), t[jj]);
        }
#pragma unroll
        for (int jj = 0; jj < 13; jj++) {
            f2 acc = *(const f2*)(gc1b + j0 + 2 * jj);
#pragma unroll
            for (int m = 0; m < 8; m++) {
                f2 tm;
                tm.x = __int_as_float(
                    __builtin_amdgcn_ds_bpermute(pidx[m], __float_as_int(t[jj].x)));
                tm.y = __int_as_float(
                    __builtin_amdgcn_ds_bpermute(pidx[m], __float_as_int(t[jj].y)));
                const f2 am = {adjr[m], adjr[m]};
                acc = __builtin_elementwise_fma(am, tm, acc);
            }
            f2 hv; hv.x = fmaxf(acc.x, 0.f); hv.y = fmaxf(acc.y, 0.f);
            *(f2*)&hsh[r][j0 + 2 * jj] = hv;
        }
    }
    __syncthreads();

    for (int l = 0; l < 3; l++) {
        const float* W  = (l == 0) ? gc2w : (l == 1) ? gc3w : gc4w;
        const float* Bb = (l == 0) ? gc2b : (l == 1) ? gc3b : gc4b;
#pragma unroll
        for (int jj = 0; jj < 13; jj++) t[jj] = (f2){0.f, 0.f};
#pragma unroll 2
        for (int k = 0; k < HD; k += 2) {
            const f2 h2 = *(const f2*)&hsh[r][k];
            const float* w0 = W + k * HD + j0;
            const float* w1 = w0 + HD;
            const f2 hx = {h2.x, h2.x};
            const f2 hy = {h2.y, h2.y};
#pragma unroll
            for (int jj = 0; jj < 13; jj++)
                t[jj] = __builtin_elementwise_fma(hx, *(const f2*)(w0 + 2 * jj), t[jj]);
#pragma unroll
            for (int jj = 0; jj < 13; jj++)
                t[jj] = __builtin_elementwise_fma(hy, *(const f2*)(w1 + 2 * jj), t[jj]);
        }
        __syncthreads();
#pragma unroll
        for (int jj = 0; jj < 13; jj++) {
            f2 acc = *(const f2*)(Bb + j0 + 2 * jj);
#pragma unroll
            for (int m = 0; m < 8; m++) {
                f2 tm;
                tm.x = __int_as_float(
                    __builtin_amdgcn_ds_bpermute(pidx[m], __float_as_int(t[jj].x)));
                tm.y = __int_as_float(
                    __builtin_amdgcn_ds_bpermute(pidx[m], __float_as_int(t[jj].y)));
                const f2 am = {adjr[m], adjr[m]};
                acc = __builtin_elementwise_fma(am, tm, acc);
            }
            f2 hv; hv.x = fmaxf(acc.x, 0.f); hv.y = fmaxf(acc.y, 0.f);
            *(f2*)&hsh[r][j0 + 2 * jj] = hv;
        }
        __syncthreads();
    }

    for (int idx = tid; idx < 8 * HD; idx += 256) {
        const int bl = idx / HD;
        const int j  = idx - bl * HD;
        const float v = hsh[bl * 8 + 7][j];
        const int gb = blockIdx.x * 8 + bl;
        if (j < 64) gA[(size_t)gb * 64 + j] = v;
        else        gB[(size_t)gb * 64 + (j - 64)] = v;
    }
}

// ---------------------------------------------------------------------------
// Kernel 2: head MLPs (unchanged, audited).
// ---------------------------------------------------------------------------
template<int NPK, bool RELU>
__device__ __forceinline__ void dense_slice(const float* inRow, int K,
    const float* W, int ldw, const float* Bias,
    float* outPtr, int outStride, int bIdx, int j0)
{
    f2 acc[NPK];
#pragma unroll
    for (int jj = 0; jj < NPK; jj++) acc[jj] = (f2){0.f, 0.f};
#pragma unroll 2
    for (int k = 0; k < K; k += 2) {
        const f2 v = *(const f2*)(inRow + k);
        const float* w0 = W + k * ldw + j0;         // uniform -> s_load
        const float* w1 = w0 + ldw;
        const f2 vx = {v.x, v.x};
        const f2 vy = {v.y, v.y};
#pragma unroll
        for (int jj = 0; jj < NPK; jj++)
            acc[jj] = __builtin_elementwise_fma(vx, *(const f2*)(w0 + 2 * jj), acc[jj]);
#pragma unroll
        for (int jj = 0; jj < NPK; jj++)
            acc[jj] = __builtin_elementwise_fma(vy, *(const f2*)(w1 + 2 * jj), acc[jj]);
    }
#pragma unroll
    for (int jj = 0; jj < NPK; jj++) {
        const f2 bz = *(const f2*)(Bias + j0 + 2 * jj);
        f2 z; z.x = acc[jj].x + bz.x; z.y = acc[jj].y + bz.y;
        if (RELU) { z.x = fmaxf(z.x, 0.f); z.y = fmaxf(z.y, 0.f); }
        *(f2*)(outPtr + bIdx * outStride + j0 + 2 * jj) = z;
    }
}

__global__ void __launch_bounds__(512, 4)
k_head(const float* hw_emb, const float* gA, const float* gB,
       const float* fc3w, const float* fc3b, const float* fc4w, const float* fc4b,
       const float* fc5w, const float* fc5b,
       const float* f0w, const float* f0b, const float* f1w, const float* f1b,
       const float* f2w, const float* f2b, const float* f3w, const float* f3b,
       const float* f4w, const float* f4b,
       const float* e0w, const float* e0b, const float* e1w, const float* e1b,
       float* out)
{
    __shared__ float bufA[64][102];
    __shared__ float bufB[64][102];
    __shared__ float xcat[64][44];
    __shared__ float hwe[64][20];
    const int tid  = threadIdx.x;
    const int wv   = tid >> 6;
    const int b    = tid & 63;
    const int base = blockIdx.x * 64;
    const int j14 = __builtin_amdgcn_readfirstlane(wv * 14 > 86 ? 86 : wv * 14);
    const int j4  = __builtin_amdgcn_readfirstlane(wv * 4 > 16 ? 16 : wv * 4);

    if (tid < 320) {
        const float4 v = *(const float4*)(hw_emb + (size_t)base * 20 + tid * 4);
        const int bb = (tid * 4) / 20, kk = (tid * 4) % 20;
        *(float4*)&hwe[bb][kk] = v;
    }
    for (int q = tid; q < 64 * 32; q += 512) {
        const int bb = q >> 5, k2 = (q & 31) * 2;
        const float2 v = *(const float2*)(gA + (size_t)(base + bb) * 64 + k2);
        *(float2*)&bufA[bb][k2] = v;
    }
    for (int q = tid; q < 64 * 18; q += 512) {
        const int bb = q / 18, k2 = (q - bb * 18) * 2;
        const float2 v = *(const float2*)(gB + (size_t)(base + bb) * 64 + k2);
        *(float2*)&bufA[bb][64 + k2] = v;
    }
    __syncthreads();

    dense_slice<7, true >(&hwe[b][0], 20, e0w, HD, e0b, &bufB[0][0], 102, b, j14);
    __syncthreads();
    dense_slice<2, true >(&bufB[b][0], HD, e1w, 20, e1b, &xcat[0][20], 44, b, j4);
    __syncthreads();
    dense_slice<7, true >(&bufA[b][0], HD, fc3w, HD, fc3b, &bufB[0][0], 102, b, j14);
    __syncthreads();
    dense_slice<7, true >(&bufB[b][0], HD, fc4w, HD, fc4b, &bufA[0][0], 102, b, j14);
    __syncthreads();
    dense_slice<2, false>(&bufA[b][0], HD, fc5w, 20, fc5b, &xcat[0][0], 44, b, j4);
    __syncthreads();
    dense_slice<7, true >(&xcat[b][0], 40, f0w, HD, f0b, &bufA[0][0], 102, b, j14);
    __syncthreads();
    dense_slice<7, true >(&bufA[b][0], HD, f1w, HD, f1b, &bufB[0][0], 102, b, j14);
    __syncthreads();
    dense_slice<7, true >(&bufB[b][0], HD, f2w, HD, f2b, &bufA[0][0], 102, b, j14);
    __syncthreads();
    dense_slice<7, true >(&bufA[b][0], HD, f3w, HD, f3b, &bufB[0][0], 102, b, j14);
    __syncthreads();
    if (wv == 0) {
        float z = f4b[0];
        const float* row = &bufB[b][0];
#pragma unroll 2
        for (int k = 0; k < HD; k += 2) {
            const float2 v = *(const float2*)(row + k);
            z = fmaf(v.x, f4w[k], z);
            z = fmaf(v.y, f4w[k + 1], z);
        }
        out[base + b] = 1.f / (1.f + __expf(-z));
    }
}

// ---------------------------------------------------------------------------
extern "C" void kernel_launch(void* const* d_in, const int* in_sizes, int n_in,
                              void* d_out, int out_size, void* d_ws, size_t ws_size,
                              hipStream_t stream)
{
    const float* feat = (const float*)d_in[0];
    const float* adj  = (const float*)d_in[1];
    const float* hw   = (const float*)d_in[2];
    const float* gc1w = (const float*)d_in[3];
    const float* gc1b = (const float*)d_in[4];
    const float* gc2w = (const float*)d_in[5];
    const float* gc2b = (const float*)d_in[6];
    const float* gc3w = (const float*)d_in[7];
    const float* gc3b = (const float*)d_in[8];
    const float* gc4w = (const float*)d_in[9];
    const float* gc4b = (const float*)d_in[10];
    const float* fc3w = (const float*)d_in[11];
    const float* fc3b = (const float*)d_in[12];
    const float* fc4w = (const float*)d_in[13];
    const float* fc4b = (const float*)d_in[14];
    const float* fc5w = (const float*)d_in[15];
    const float* fc5b = (const float*)d_in[16];
    const float* f0w  = (const float*)d_in[17];
    const float* f0b  = (const float*)d_in[18];
    const float* f1w  = (const float*)d_in[19];
    const float* f1b  = (const float*)d_in[20];
    const float* f2w  = (const float*)d_in[21];
    const float* f2b  = (const float*)d_in[22];
    const float* f3w  = (const float*)d_in[23];
    const float* f3b  = (const float*)d_in[24];
    const float* f4w  = (const float*)d_in[25];
    const float* f4b  = (const float*)d_in[26];
    const float* e0w  = (const float*)d_in[27];
    const float* e0b  = (const float*)d_in[28];
    const float* e1w  = (const float*)d_in[29];
    const float* e1b  = (const float*)d_in[30];

    const size_t need = (size_t)NB * 128 * sizeof(float);
    if (ws_size >= need) {
        // A/B mode: k_gcn3 (candidate) first; its gA/gB are fully overwritten
        // by the audited k_gcn, so correctness never depends on k_gcn3.
        float* gAp = (float*)d_ws;
        float* gBp = (float*)d_ws + (size_t)NB * 64;
        hipLaunchKernelGGL(k_gcn3, dim3(NB / 8), dim3(512), 0, stream,
                           feat, adj, gc1w, gc1b, gc2w, gc2b, gc3w, gc3b, gc4w, gc4b,
                           gAp, gBp);
        hipLaunchKernelGGL(k_gcn, dim3(NB / 8), dim3(256), 0, stream,
                           feat, adj, gc1w, gc1b, gc2w, gc2b, gc3w, gc3b, gc4w, gc4b,
                           gAp, gBp);
        hipLaunchKernelGGL(k_head, dim3(NB / 64), dim3(512), 0, stream,
                           hw, gAp, gBp, fc3w, fc3b, fc4w, fc4b, fc5w, fc5b,
                           f0w, f0b, f1w, f1b, f2w, f2b, f3w, f3b, f4w, f4b,
                           e0w, e0b, e1w, e1b, (float*)d_out);
    } else {
        // Overlay fallback: audited path only.
        float* gAp = (float*)d_in[0];
        float* gBp = (float*)d_in[1];
        hipLaunchKernelGGL(k_gcn, dim3(NB / 8), dim3(256), 0, stream,
                           feat, adj, gc1w, gc1b, gc2w, gc2b, gc3w, gc3b, gc4w, gc4b,
                           gAp, gBp);
        hipLaunchKernelGGL(k_head, dim3(NB / 64), dim3(512), 0, stream,
                           hw, gAp, gBp, fc3w, fc3b, fc4w, fc4b, fc5w, fc5b,
                           f0w, f0b, f1w, f1b, f2w, f2b, f3w, f3b, f4w, f4b,
                           e0w, e0b, e1w, e1b, (float*)d_out);
    }
}